// Round 9
// baseline (259.391 us; speedup 1.0000x reference)
//
#include <hip/hip_runtime.h>
#include <hip/hip_bf16.h>

// Problem constants
#define B_    256
#define CIN   64
#define COUT  64
#define H_    1855
#define K_    6
#define NSTEP 14           // 448 / 32 (K per MFMA)
#define HT    64           // h-tile for transpose kernel
#define NHT   29           // ceil(1855/64)

// conv_main tiling (barrier-free): 15 hg-blocks of 8 hg x 16 h = 120 hg >= 116
#define HGPB  15
#define NBLK2 (2 * B_ * HGPB)   // 7680 blocks, % 8 == 0
#define CPX3  (NBLK2 / 8)       // 960

typedef __bf16 bf16x8 __attribute__((ext_vector_type(8)));
typedef float  f32x4  __attribute__((ext_vector_type(4)));

static __device__ inline unsigned short f2bf(float f) {
    __hip_bfloat16 h = __float2bfloat16(f);
    return *reinterpret_cast<unsigned short*>(&h);
}

// ---------------------------------------------------------------------------
// Kernel 1: pack weights into MFMA A-fragment order (bf16) + 1/total_valid.
// Also zeroes the 128-B zbuf (branch-free source for invalid neighbors).
// ---------------------------------------------------------------------------
__global__ void prep_weights(const float* __restrict__ wc,
                             const float* __restrict__ wn,
                             const int*   __restrict__ nb,
                             unsigned short* __restrict__ W2,
                             float* __restrict__ inv_tv,
                             unsigned short* __restrict__ zbuf) {
    int e = blockIdx.x * 256 + threadIdx.x;     // 0 .. 28671
    int j = e & 7;
    int l = (e >> 3) & 63;
    int t = (e >> 9) & 3;
    int s = e >> 11;
    int o = t * 16 + (l & 15);
    int k = s * 32 + (l >> 4) * 8 + j;
    int slot = k >> 6;
    int c = k & 63;
    float v = (slot == 0) ? wc[o * 64 + c]
                          : wn[(o * 64 + c) * 6 + (slot - 1)];
    W2[e] = f2bf(v);
    if (blockIdx.x == 0 && threadIdx.x < 64) zbuf[threadIdx.x] = 0;
    if (e == 0) {
        int cnt = 1;
        #pragma unroll
        for (int q = 0; q < 6; ++q) cnt += (nb[q] >= 0) ? 1 : 0;
        *inv_tv = 1.0f / (float)cnt;
    }
}

// ---------------------------------------------------------------------------
// Kernel 2: transpose + convert  x (B, C, H) fp32  ->  xT (B, H, C) bf16
// ---------------------------------------------------------------------------
__global__ void transpose_bf16(const float* __restrict__ x,
                               unsigned short* __restrict__ xT) {
    __shared__ __align__(16) unsigned short tile[64][72];  // +8 pad
    int b  = blockIdx.y;
    int h0 = blockIdx.x * HT;
    int t  = threadIdx.x;
    int ho = t & 63;
    int cq = t >> 6;                       // 0..3
    const float* xb = x + (size_t)b * CIN * H_;
    int h = h0 + ho;
    #pragma unroll
    for (int i = 0; i < 16; ++i) {
        int c = i * 4 + cq;
        float v = (h < H_) ? xb[(size_t)c * H_ + h] : 0.f;
        tile[ho][c] = f2bf(v);
    }
    __syncthreads();
    #pragma unroll
    for (int rep = 0; rep < 2; ++rep) {
        int task = rep * 256 + t;          // 0..511  = 64 rows * 8 chunks
        int hh = task >> 3;
        int j  = task & 7;
        int hw = h0 + hh;
        if (hw < H_) {
            *reinterpret_cast<uint4*>(&xT[((size_t)b * H_ + hw) * 64 + j * 8]) =
                *reinterpret_cast<const uint4*>(&tile[hh][j * 8]);
        }
    }
}

// ---------------------------------------------------------------------------
// Kernel 3: BARRIER-FREE direct-gather MFMA.
// Every schedule with block-wide barriers (rounds 2-8) pinned at 76-89 us
// regardless of staging depth / wave layout / W residency -> the stall is
// barrier-coupling to gather stragglers with ~1.3 independent blocks/CU.
// Here: no barriers in the hot path. W (og-pair half, 28 frags) sits in
// per-block LDS (28.7 KB -> 5 blocks/CU = 20 waves/CU of independent TLP);
// A-frags re-read from LDS per use (stride-16 ds_read_b128, conflict-free);
// B-frags gathered per-lane from global xT (L2-resident; R6's failure was
// W-remat from global, not the gather itself). Each wave: one b, two 16-h
// groups, 2 o-tiles per B-frag (28 ds_read + 14 gathers + 28 MFMA per group).
// ---------------------------------------------------------------------------
__global__ __launch_bounds__(256, 5) void conv_main(
        const unsigned short* __restrict__ xT,
        const unsigned short* __restrict__ W2,
        const int*   __restrict__ nb,
        const float* __restrict__ bias,
        const float* __restrict__ inv_tv,
        const unsigned short* __restrict__ zbuf,
        float* __restrict__ out) {
    __shared__ __align__(16) unsigned short wlds[28 * 64 * 8];  // 28,672 B

    int bid = blockIdx.x;
    int swz = (bid & 7) * CPX3 + (bid >> 3);   // bijective XCD swizzle
    int ogp = swz / (B_ * HGPB);               // 0..1
    int rem = swz - ogp * (B_ * HGPB);
    int b   = rem / HGPB;
    int hgb = rem - b * HGPB;                  // 0..14

    int t = threadIdx.x;
    int w = t >> 6;          // wave 0..3
    int l = t & 63;
    int lr = l & 15, lg = l >> 4;

    // ---- W quarter-pair -> LDS (28 frags x 64 lanes x 16 B), once --------
    const uint4* __restrict__ Wf4 = reinterpret_cast<const uint4*>(W2);
    uint4* wl4 = reinterpret_cast<uint4*>(wlds);
    #pragma unroll
    for (int k = 0; k < 7; ++k) {
        int u   = k * 256 + t;        // 0..1791
        int sid = u >> 6;             // 0..27
        int ll  = u & 63;
        int s   = sid >> 1;           // K-step 0..13
        int u2  = sid & 1;            // o-half within pair
        wl4[u] = Wf4[(s * 4 + ogp * 2 + u2) * 64 + ll];
    }
    float inv = *inv_tv;
    float bv0[4], bv1[4];
    #pragma unroll
    for (int r = 0; r < 4; ++r) {
        bv0[r] = bias[ogp * 32 + lg * 4 + r];
        bv1[r] = bias[ogp * 32 + 16 + lg * 4 + r];
    }
    __syncthreads();                  // the ONLY block sync

    const unsigned short* __restrict__ xb = xT + (size_t)b * H_ * 64;
    const bf16x8* __restrict__ wf = reinterpret_cast<const bf16x8*>(wlds);

    // ---- two independent 16-h groups per wave ----------------------------
    // Load both groups' row indices upfront so group-1 gathers can be
    // hoisted by the scheduler under group-0's MFMA chain.
    int hg0 = hgb * 8 + w * 2;
    int cn2[2][7];
    #pragma unroll
    for (int g = 0; g < 2; ++g) {
        int h = (hg0 + g) * 16 + lr;
        bool vh = (h < H_);
        cn2[g][0] = vh ? h : -1;
        #pragma unroll
        for (int q = 0; q < 6; ++q)
            cn2[g][q + 1] = vh ? nb[h * 6 + q] : -1;
    }

    #pragma unroll
    for (int g = 0; g < 2; ++g) {
        int h = (hg0 + g) * 16 + lr;
        f32x4 acc0 = (f32x4){0.f, 0.f, 0.f, 0.f};
        f32x4 acc1 = (f32x4){0.f, 0.f, 0.f, 0.f};

        #pragma unroll
        for (int q = 0; q < 7; ++q) {         // slot 0 = center, 1..6 = nbrs
            int n = cn2[g][q];
            const bf16x8* r = (n >= 0)
                ? reinterpret_cast<const bf16x8*>(xb + (size_t)n * 64)
                : reinterpret_cast<const bf16x8*>(zbuf);
            bf16x8 fa = r[lg];
            bf16x8 fb = r[4 + lg];
            int s = 2 * q;
            acc0 = __builtin_amdgcn_mfma_f32_16x16x32_bf16(wf[(s * 2 + 0) * 64 + l], fa, acc0, 0, 0, 0);
            acc1 = __builtin_amdgcn_mfma_f32_16x16x32_bf16(wf[(s * 2 + 1) * 64 + l], fa, acc1, 0, 0, 0);
            acc0 = __builtin_amdgcn_mfma_f32_16x16x32_bf16(wf[((s + 1) * 2 + 0) * 64 + l], fb, acc0, 0, 0, 0);
            acc1 = __builtin_amdgcn_mfma_f32_16x16x32_bf16(wf[((s + 1) * 2 + 1) * 64 + l], fb, acc1, 0, 0, 0);
        }

        if (h < H_) {
            float* ob = out + (size_t)b * COUT * H_ + h;
            #pragma unroll
            for (int r = 0; r < 4; ++r) {
                ob[(size_t)(ogp * 32 + lg * 4 + r) * H_]      = acc0[r] * inv + bv0[r];
                ob[(size_t)(ogp * 32 + 16 + lg * 4 + r) * H_] = acc1[r] * inv + bv1[r];
            }
        }
    }
}

// ---------------------------------------------------------------------------
extern "C" void kernel_launch(void* const* d_in, const int* in_sizes, int n_in,
                              void* d_out, int out_size, void* d_ws, size_t ws_size,
                              hipStream_t stream) {
    const float* x    = (const float*)d_in[0];
    const int*   nb   = (const int*)  d_in[1];
    const float* wc   = (const float*)d_in[2];
    const float* wn   = (const float*)d_in[3];
    const float* bias = (const float*)d_in[4];
    float* out = (float*)d_out;

    char* ws = (char*)d_ws;
    unsigned short* W2     = (unsigned short*)ws;            // 57,344 B
    float*          inv_tv = (float*)(ws + 57344);           // 4 B
    unsigned short* zbuf   = (unsigned short*)(ws + 57472);  // 128 B zero
    unsigned short* xT     = (unsigned short*)(ws + 57600);  // 60,784,640 B

    prep_weights<<<112, 256, 0, stream>>>(wc, wn, nb, W2, inv_tv, zbuf);

    dim3 tgrid(NHT, B_);
    transpose_bf16<<<tgrid, 256, 0, stream>>>(x, xT);
    conv_main<<<NBLK2, 256, 0, stream>>>(xT, W2, nb, bias, inv_tv, zbuf, out);
}

// Round 10
// 175.833 us; speedup vs baseline: 1.4752x; 1.4752x over previous
//
#include <hip/hip_runtime.h>
#include <hip/hip_bf16.h>

// Problem constants
#define B_    256
#define CIN   64
#define COUT  64
#define H_    1855
#define K_    6
#define NSTEP 14           // 448 / 32 (K per MFMA)
#define HT    64           // h-tile for transpose kernel
#define NHT   29           // ceil(1855/64)

// conv_main tiling: 16-h tiles, 16 tiles per block, 4-wave blocks
#define HT3    16
#define TPB2   116              // tiles per b = ceil(1855/16) -> 116*16 = 1856 rows (1 pad)
#define NTILE2 (TPB2 * B_)      // 29696
#define TPBLK2 16
#define NBLK3  (NTILE2 / TPBLK2)   // 1856, % 8 == 0
#define CPX4   (NBLK3 / 8)         // 232

typedef __bf16 bf16x8 __attribute__((ext_vector_type(8)));
typedef float  f32x4  __attribute__((ext_vector_type(4)));

typedef __attribute__((address_space(3))) unsigned int       lds_u32;
typedef const __attribute__((address_space(1))) unsigned int glb_u32;

static __device__ inline unsigned short f2bf(float f) {
    __hip_bfloat16 h = __float2bfloat16(f);
    return *reinterpret_cast<unsigned short*>(&h);
}

// ---------------------------------------------------------------------------
// Kernel 1: pack weights into MFMA A-fragment order (bf16) + 1/total_valid.
// Also zeroes the 128-B zbuf (branch-free source for invalid neighbors).
// ---------------------------------------------------------------------------
__global__ void prep_weights(const float* __restrict__ wc,
                             const float* __restrict__ wn,
                             const int*   __restrict__ nb,
                             unsigned short* __restrict__ W2,
                             float* __restrict__ inv_tv,
                             unsigned short* __restrict__ zbuf) {
    int e = blockIdx.x * 256 + threadIdx.x;     // 0 .. 28671
    int j = e & 7;
    int l = (e >> 3) & 63;
    int t = (e >> 9) & 3;
    int s = e >> 11;
    int o = t * 16 + (l & 15);
    int k = s * 32 + (l >> 4) * 8 + j;
    int slot = k >> 6;
    int c = k & 63;
    float v = (slot == 0) ? wc[o * 64 + c]
                          : wn[(o * 64 + c) * 6 + (slot - 1)];
    W2[e] = f2bf(v);
    if (blockIdx.x == 0 && threadIdx.x < 64) zbuf[threadIdx.x] = 0;
    if (e == 0) {
        int cnt = 1;
        #pragma unroll
        for (int q = 0; q < 6; ++q) cnt += (nb[q] >= 0) ? 1 : 0;
        *inv_tv = 1.0f / (float)cnt;
    }
}

// ---------------------------------------------------------------------------
// Kernel 2: transpose + convert  x (B, C, H) fp32  ->  xT (B, H, C) bf16
// ---------------------------------------------------------------------------
__global__ void transpose_bf16(const float* __restrict__ x,
                               unsigned short* __restrict__ xT) {
    __shared__ __align__(16) unsigned short tile[64][72];  // +8 pad
    int b  = blockIdx.y;
    int h0 = blockIdx.x * HT;
    int t  = threadIdx.x;
    int ho = t & 63;
    int cq = t >> 6;                       // 0..3
    const float* xb = x + (size_t)b * CIN * H_;
    int h = h0 + ho;
    #pragma unroll
    for (int i = 0; i < 16; ++i) {
        int c = i * 4 + cq;
        float v = (h < H_) ? xb[(size_t)c * H_ + h] : 0.f;
        tile[ho][c] = f2bf(v);
    }
    __syncthreads();
    #pragma unroll
    for (int rep = 0; rep < 2; ++rep) {
        int task = rep * 256 + t;          // 0..511  = 64 rows * 8 chunks
        int hh = task >> 3;
        int j  = task & 7;
        int hw = h0 + hh;
        if (hw < H_) {
            *reinterpret_cast<uint4*>(&xT[((size_t)b * H_ + hw) * 64 + j * 8]) =
                *reinterpret_cast<const uint4*>(&tile[hh][j * 8]);
        }
    }
}

// ---------------------------------------------------------------------------
// Kernel 3: 16-tile pipeline at SMALL grain for cross-block TLP.
// 256 thr = 4 waves; wave w = o-group w (one 16x16 o-tile, full K).
// LDS 28 KB/block -> 5 blocks/CU = 20 waves/CU: 5 INDEPENDENT pipelines
// per CU overlap each other's gather-straggler stalls (R2-R8 had only 2,
// barrier-coupled -> 76-89 us invariant).
// Staging: 14 half-slot units (7 slots x 8 rows); wave w stages 3 neighbor
// units m=w*3+c (slot=1+(m>>1), half=m&1) + (w<2) one center half.
// Counted vmcnt, exact per-phase (incl. the i==0 prologue FIFO edge).
// ---------------------------------------------------------------------------
__global__ __launch_bounds__(256, 5) void conv_main(
        const unsigned short* __restrict__ xT,
        const unsigned short* __restrict__ W2,
        const int*   __restrict__ nb,
        const float* __restrict__ bias,
        const float* __restrict__ inv_tv,
        const unsigned short* __restrict__ zbuf,
        float* __restrict__ out) {
    __shared__ __align__(16) unsigned short feat[2][7][HT3][64]; // 28,672 B

    int bid = blockIdx.x;
    int swz   = (bid & 7) * CPX4 + (bid >> 3);   // bijective XCD swizzle
    int gbase = swz * TPBLK2;

    int t = threadIdx.x;
    int w = t >> 6;          // wave 0..3
    int l = t & 63;

    // staging lane constants
    int lrow = l >> 3;                  // row within an 8-row half
    int jsrc = (l & 7) ^ lrow;          // source 16B unit (inverse of read swz)
    int slotc[3], halfc[3], nbq[3];
    #pragma unroll
    for (int c = 0; c < 3; ++c) {
        int m = w * 3 + c;              // 0..11 neighbor half-units
        nbq[c]   = m >> 1;              // neighbor index 0..5
        slotc[c] = 1 + (m >> 1);        // slot 1..6
        halfc[c] = (m & 1) * 8;         // row base 0/8
    }
    bool hasC = (w < 2);                // waves 0,1 stage center half w

    // compute lane constants
    int og = w;                          // o-group 0..3
    int lr = l & 15, lg = l >> 4;
    int sw8 = lr & 7;

    // W fragments -> registers
    const bf16x8* __restrict__ Wf = reinterpret_cast<const bf16x8*>(W2);
    bf16x8 wr[NSTEP];
    #pragma unroll
    for (int s = 0; s < NSTEP; ++s) wr[s] = Wf[(s * 4 + og) * 64 + l];

    float inv = *inv_tv;
    float bv[4];
    #pragma unroll
    for (int r = 0; r < 4; ++r) bv[r] = bias[og * 16 + lg * 4 + r];

    // nbv[p]: neighbor rows for tile t with t&1==p (ping-pong, static idx)
    int nbv[2][3];

    // ---- prologue: nb_0 -> stage_0 -> nb_1 -------------------------------
    {
        int g0  = gbase;
        int b0  = g0 / TPB2;
        int h00 = (g0 - b0 * TPB2) * HT3;
        int nb0[3];
        #pragma unroll
        for (int c = 0; c < 3; ++c) {
            int h = h00 + halfc[c] + lrow;
            nb0[c] = (h < H_) ? nb[h * 6 + nbq[c]] : -1;
        }
        const unsigned short* xb = xT + (size_t)b0 * H_ * 64;
        #pragma unroll
        for (int c = 0; c < 3; ++c) {
            int n = nb0[c];
            const unsigned short* src = (n >= 0)
                ? (xb + (size_t)n * 64 + jsrc * 8) : (zbuf + jsrc * 8);
            __builtin_amdgcn_global_load_lds((glb_u32*)src,
                (lds_u32*)&feat[0][slotc[c]][halfc[c]][0], 16, 0, 0);
        }
        if (hasC) {
            int hc = h00 + w * 8 + lrow; if (hc >= H_) hc = H_ - 1;
            __builtin_amdgcn_global_load_lds(
                (glb_u32*)(xb + (size_t)hc * 64 + jsrc * 8),
                (lds_u32*)&feat[0][0][w * 8][0], 16, 0, 0);
        }
        int g1  = gbase + 1;
        int b1  = g1 / TPB2;
        int h01 = (g1 - b1 * TPB2) * HT3;
        #pragma unroll
        for (int c = 0; c < 3; ++c) {
            int h = h01 + halfc[c] + lrow;
            nbv[1][c] = (h < H_) ? nb[h * 6 + nbq[c]] : -1;
        }
    }

    // ---- main loop over 16 tiles (fully unrolled, static parity) ---------
    #pragma unroll
    for (int i = 0; i < TPBLK2; ++i) {
        // B': prefetch nb rows for tile i+2 into nbv[i&1]
        if (i < TPBLK2 - 2) {
            int g2  = gbase + i + 2;
            int b2  = g2 / TPB2;
            int h02 = (g2 - b2 * TPB2) * HT3;
            #pragma unroll
            for (int c = 0; c < 3; ++c) {
                int h = h02 + halfc[c] + lrow;
                nbv[i & 1][c] = (h < H_) ? nb[h * 6 + nbq[c]] : -1;
            }
        }
        // A': stage tile i+1 into feat[(i+1)&1] (stage_i stays in flight)
        if (i < TPBLK2 - 1) {
            int g1  = gbase + i + 1;
            int b1  = g1 / TPB2;
            int h01 = (g1 - b1 * TPB2) * HT3;
            const unsigned short* xb = xT + (size_t)b1 * H_ * 64;
            int nbuf = (i + 1) & 1;
            #pragma unroll
            for (int c = 0; c < 3; ++c) {
                int n = nbv[nbuf][c];
                const unsigned short* src = (n >= 0)
                    ? (xb + (size_t)n * 64 + jsrc * 8) : (zbuf + jsrc * 8);
                __builtin_amdgcn_global_load_lds((glb_u32*)src,
                    (lds_u32*)&feat[nbuf][slotc[c]][halfc[c]][0], 16, 0, 0);
            }
            if (hasC) {
                int hc = h01 + w * 8 + lrow; if (hc >= H_) hc = H_ - 1;
                __builtin_amdgcn_global_load_lds(
                    (glb_u32*)(xb + (size_t)hc * 64 + jsrc * 8),
                    (lds_u32*)&feat[nbuf][0][w * 8][0], 16, 0, 0);
            }
        }
        // C: counted wait for stage_i. Ns = 4 (w<2) / 3. Newer-than-stage_i:
        //   i==0:        nb_1(3) + B'(3) + A'(Ns)        = 6+Ns -> 10/9
        //   1<=i<=13:    F(4)    + B'(3) + A'(Ns)        = 7+Ns -> 11/10
        //   i==14:       F(4)            + A'(Ns)        = 4+Ns -> 8/7
        //   i==15:       F(4)                            = 4
        if (i == TPBLK2 - 1) {
            asm volatile("s_waitcnt vmcnt(4)" ::: "memory");
        } else if (i == TPBLK2 - 2) {
            if (hasC) asm volatile("s_waitcnt vmcnt(8)" ::: "memory");
            else      asm volatile("s_waitcnt vmcnt(7)" ::: "memory");
        } else if (i == 0) {
            if (hasC) asm volatile("s_waitcnt vmcnt(10)" ::: "memory");
            else      asm volatile("s_waitcnt vmcnt(9)" ::: "memory");
        } else {
            if (hasC) asm volatile("s_waitcnt vmcnt(11)" ::: "memory");
            else      asm volatile("s_waitcnt vmcnt(10)" ::: "memory");
        }
        __builtin_amdgcn_s_barrier();
        __builtin_amdgcn_sched_barrier(0);

        // E: compute tile i — 14 swizzled ds_read_b128 + 14 MFMA
        int cb = i & 1;
        f32x4 acc = (f32x4){0.f, 0.f, 0.f, 0.f};
        #pragma unroll
        for (int s = 0; s < 7; ++s) {       // slot 0 = center, 1..6 = nbrs
            bf16x8 fa = *reinterpret_cast<const bf16x8*>(
                    &feat[cb][s][lr][(lg ^ sw8) * 8]);
            bf16x8 fb = *reinterpret_cast<const bf16x8*>(
                    &feat[cb][s][lr][((4 + lg) ^ sw8) * 8]);
            acc = __builtin_amdgcn_mfma_f32_16x16x32_bf16(wr[2 * s],     fa, acc, 0, 0, 0);
            acc = __builtin_amdgcn_mfma_f32_16x16x32_bf16(wr[2 * s + 1], fb, acc, 0, 0, 0);
        }

        // F: epilogue for tile i (4 stores)
        int g    = gbase + i;
        int curb = g / TPB2;
        int curh = (g - curb * TPB2) * HT3 + lr;
        if (curh < H_) {
            float* ob = out + (size_t)curb * COUT * H_ + curh;
            #pragma unroll
            for (int r = 0; r < 4; ++r)
                ob[(size_t)(og * 16 + lg * 4 + r) * H_] = acc[r] * inv + bv[r];
        }

        // G: all reads of feat[i&1] done before next iter's staging
        __builtin_amdgcn_s_barrier();
    }
}

// ---------------------------------------------------------------------------
extern "C" void kernel_launch(void* const* d_in, const int* in_sizes, int n_in,
                              void* d_out, int out_size, void* d_ws, size_t ws_size,
                              hipStream_t stream) {
    const float* x    = (const float*)d_in[0];
    const int*   nb   = (const int*)  d_in[1];
    const float* wc   = (const float*)d_in[2];
    const float* wn   = (const float*)d_in[3];
    const float* bias = (const float*)d_in[4];
    float* out = (float*)d_out;

    char* ws = (char*)d_ws;
    unsigned short* W2     = (unsigned short*)ws;            // 57,344 B
    float*          inv_tv = (float*)(ws + 57344);           // 4 B
    unsigned short* zbuf   = (unsigned short*)(ws + 57472);  // 128 B zero
    unsigned short* xT     = (unsigned short*)(ws + 57600);  // 60,784,640 B

    prep_weights<<<112, 256, 0, stream>>>(wc, wn, nb, W2, inv_tv, zbuf);

    dim3 tgrid(NHT, B_);
    transpose_bf16<<<tgrid, 256, 0, stream>>>(x, xT);
    conv_main<<<NBLK3, 256, 0, stream>>>(xT, W2, nb, bias, inv_tv, zbuf, out);
}